// Round 6
// baseline (35.358 us; speedup 1.0000x reference)
//
#include <hip/hip_runtime.h>
#include <hip/hip_bf16.h>

typedef __bf16 bf16x8 __attribute__((ext_vector_type(8)));
typedef float f32x4 __attribute__((ext_vector_type(4)));

#define K_DIM 1024
#define N_DIM 128

// ws layout:
//   [0, 1MB)        Tfrag: [rg:256][ks:4][lane:64][elem:8] bf16
//   [1MB, +16KB)    nrm:   [4096] f32
//
// Fragment convention (validated R0-R5, mfma_f32_16x16x32_bf16):
//   operand: 16-idx = lane%16, k = 4*(lane/16) + (e&3) + 16*(e>>2)
//   D: col = lane&15 (= operand2's 16-idx), row = 4*(lane>>4)+i (= operand1's)

__device__ inline unsigned pk2(float x, float y) {
  __hip_bfloat16 hx = __float2bfloat16(x), hy = __float2bfloat16(y);
  return (unsigned)*(unsigned short*)&hx | ((unsigned)*(unsigned short*)&hy << 16);
}

// ---------------------------------------------------------------------------
// K1: T = batch @ B. 256 blocks x 512 thr (8 waves, 1 block/CU).
// - B-fragments converted f32->bf16 straight into REGISTERS per wave
//   (32 x bf16x8 = 128 VGPR; redundant per block, L2-resident source, no
//   cross-block dependency, no extra dispatch).
// - A-tile (16 rows x 1024, 64KB, linearly contiguous) staged once into LDS
//   in fragment layout (XOR-swizzled), coalesced 1KB/instr.
// - k-loop: ds_read_b128(A) + MFMA only.
// ---------------------------------------------------------------------------
__global__ __launch_bounds__(512, 2)
void proj_kernel(const float* __restrict__ batch, const float* __restrict__ Bmat,
                 unsigned short* __restrict__ Tfrag, float* __restrict__ nrm) {
  __shared__ __align__(16) unsigned short Asl[32 * 64 * 8];  // 32 KB
  __shared__ float part[8][16];
  const int t = threadIdx.x, w = t >> 6, l = t & 63;
  const int blk = blockIdx.x;
  const int m0 = blk * 16;

  // ---- stage A: linear 64 KB -> bf16 fragments (coalesced 1KB/instr) ----
  {
    const float* src = batch + (size_t)m0 * K_DIM;
#pragma unroll
    for (int j = 0; j < 8; ++j) {
      int fidx = j * 512 + t;                     // f32x4 chunk index
      f32x4 v = *(const f32x4*)(src + 4 * (size_t)fidx);
      int r = fidx >> 8;                          // block row 0..15
      int q = fidx & 255;                         // k-quad within row
      int ks = q >> 3, qq = q & 7, g = qq & 3, h = qq >> 2;
      int byte = ks * 1024 + ((16 * (r + 16 * g)) ^ ((ks & 7) << 4)) + 8 * h;
      *(uint2*)((char*)Asl + byte) = make_uint2(pk2(v.x, v.y), pk2(v.z, v.w));
    }
  }

  // ---- stage B fragments into registers (per-wave slice, L2-hit reads) ----
  // elems e=0..7 of (w,ks,l): k = 32ks + 4*(l>>4) + (e&3) + 16*(e>>2),
  // col = 16w + (l&15). Pair rows (k,k+1) -> one u32 (same RNE as old prep).
  bf16x8 bfr[32];
  {
    const float* bcol = Bmat + 16 * w + (l & 15);
    const int kb0 = 4 * (l >> 4);
#pragma unroll
    for (int ks = 0; ks < 32; ++ks) {
      const float* p = bcol + (size_t)(32 * ks + kb0) * N_DIM;
      uint4 u;
      u.x = pk2(p[0 * N_DIM], p[1 * N_DIM]);      // k+0, k+1
      u.y = pk2(p[2 * N_DIM], p[3 * N_DIM]);      // k+2, k+3
      u.z = pk2(p[16 * N_DIM], p[17 * N_DIM]);    // k+16, k+17
      u.w = pk2(p[18 * N_DIM], p[19 * N_DIM]);    // k+18, k+19
      bfr[ks] = *(bf16x8*)&u;
    }
  }
  __syncthreads();

  // ---- k-loop: pure LDS + MFMA, zero barriers ----
  f32x4 acc0 = {0.f, 0.f, 0.f, 0.f}, acc1 = {0.f, 0.f, 0.f, 0.f};
#pragma unroll
  for (int ks = 0; ks < 32; ks += 2) {
    bf16x8 a0 = *(const bf16x8*)((const char*)Asl +
                   (ks * 1024 + ((l * 16) ^ ((ks & 7) << 4))));
    acc0 = __builtin_amdgcn_mfma_f32_16x16x32_bf16(bfr[ks], a0, acc0, 0, 0, 0);
    bf16x8 a1 = *(const bf16x8*)((const char*)Asl +
                   ((ks + 1) * 1024 + ((l * 16) ^ (((ks + 1) & 7) << 4))));
    acc1 = __builtin_amdgcn_mfma_f32_16x16x32_bf16(bfr[ks + 1], a1, acc1, 0, 0, 0);
  }
  f32x4 acc = acc0 + acc1;

  // ---- store T fragment (validated layout) + row norms ----
  unsigned lo = pk2(acc[0], acc[1]);
  unsigned hi = pk2(acc[2], acc[3]);
  *(uint2*)&Tfrag[(((size_t)blk * 4 + (w >> 1)) * 64 + l) * 8 + (w & 1) * 4] =
      make_uint2(lo, hi);

  float v0 = __uint_as_float(lo << 16);
  float v1 = __uint_as_float(lo & 0xffff0000u);
  float v2 = __uint_as_float(hi << 16);
  float v3 = __uint_as_float(hi & 0xffff0000u);
  float s = v0 * v0 + v1 * v1 + v2 * v2 + v3 * v3;
  s += __shfl_xor(s, 16);
  s += __shfl_xor(s, 32);   // sum over this wave's 16 cols of row l&15
  if (l < 16) part[w][l] = s;
  __syncthreads();
  if (t < 16) {
    float n = 0.f;
#pragma unroll
    for (int ww = 0; ww < 8; ++ww) n += part[ww][t];  // fixed order
    nrm[m0 + t] = n;
  }
}

// ---------------------------------------------------------------------------
// K2: out[b,i,j] = n_i + n_j - 2*(T_i.T_j). 1024 blocks x 256 thr
// (4096 waves, 4/SIMD). Wave = 16x16 tile: 8 frag loads, 4 MFMA, no LDS.
// ---------------------------------------------------------------------------
__global__ __launch_bounds__(256)
void dist_kernel(const unsigned short* __restrict__ Tfrag,
                 const float* __restrict__ nrm, float* __restrict__ out) {
  const int t = threadIdx.x, l = t & 63;
  const int W = blockIdx.x * 4 + (t >> 6);  // 0..4095
  const int bb = W >> 8, tile = W & 255;
  const int ti = (tile >> 4) * 16, tj = (tile & 15) * 16;
  const int rbase = bb * 256;

  bf16x8 ifr[4], jfr[4];
#pragma unroll
  for (int ks = 0; ks < 4; ++ks) {
    ifr[ks] = *(const bf16x8*)
        &Tfrag[((((size_t)bb * 16 + (ti >> 4)) * 4 + ks) * 64 + l) * 8];
    jfr[ks] = *(const bf16x8*)
        &Tfrag[((((size_t)bb * 16 + (tj >> 4)) * 4 + ks) * 64 + l) * 8];
  }

  f32x4 acc = {0.f, 0.f, 0.f, 0.f};
#pragma unroll
  for (int ks = 0; ks < 4; ++ks)
    acc = __builtin_amdgcn_mfma_f32_16x16x32_bf16(ifr[ks], jfr[ks], acc, 0, 0, 0);

  const float njv = nrm[rbase + tj + (l & 15)];
  const f32x4 ni = *(const f32x4*)&nrm[rbase + ti + 4 * (l >> 4)];
#pragma unroll
  for (int ii = 0; ii < 4; ++ii) {
    out[(size_t)(rbase + ti + 4 * (l >> 4) + ii) * 256 + tj + (l & 15)] =
        ni[ii] + njv - 2.f * acc[ii];
  }
}

extern "C" void kernel_launch(void* const* d_in, const int* in_sizes, int n_in,
                              void* d_out, int out_size, void* d_ws, size_t ws_size,
                              hipStream_t stream) {
  const float* batch = (const float*)d_in[0];  // (16,256,1024) f32
  const float* Bmat  = (const float*)d_in[1];  // (1024,128) f32
  unsigned short* Tfrag = (unsigned short*)d_ws;              // 1 MB
  float* nrm = (float*)(Tfrag + 256 * 4 * 64 * 8);            // 16 KB
  float* out = (float*)d_out;                                 // (16,256,256) f32

  proj_kernel<<<256, 512, 0, stream>>>(batch, Bmat, Tfrag, nrm);
  dist_kernel<<<1024, 256, 0, stream>>>(Tfrag, nrm, out);
}

// Round 7
// 20.521 us; speedup vs baseline: 1.7230x; 1.7230x over previous
//
#include <hip/hip_runtime.h>
#include <hip/hip_bf16.h>

typedef __bf16 bf16x8 __attribute__((ext_vector_type(8)));
typedef float f32x4 __attribute__((ext_vector_type(4)));

#define K_DIM 1024
#define N_DIM 128

// ws layout:
//   [0, 256KB)        Bfrag: [w:8][ks:32][lane:64][elem:8] bf16
//   [256KB, +1MB)     Tfrag: [rg:256][ks:4][lane:64][elem:8] bf16
//   [256KB+1MB, +16K) nrm:   [4096] f32
//
// Fragment convention (validated R0-R6, mfma_f32_16x16x32_bf16):
//   operand: 16-idx = lane%16, k = 4*(lane/16) + (e&3) + 16*(e>>2)
//   D: col = lane&15 (= operand2's 16-idx), row = 4*(lane>>4)+i (= operand1's)
//
// Structure lesson (R4/R5/R6): prep as its own tiny dispatch is ~2us; every
// attempt to fold it into proj (grid.sync / flag handshake / per-wave strided
// reconvert) cost 14-55us. Dispatch boundaries are the cheap sync points.

__device__ inline unsigned pk2(float x, float y) {
  __hip_bfloat16 hx = __float2bfloat16(x), hy = __float2bfloat16(y);
  return (unsigned)*(unsigned short*)&hx | ((unsigned)*(unsigned short*)&hy << 16);
}

// ---------------------------------------------------------------------------
// prep: B (1024x128 f32) -> Bfrag. 256 blocks x 64 thr (1 wave each, one
// load->convert->store round trip). Wave W = (w=W>>5, ks=W&31).
// ---------------------------------------------------------------------------
__global__ __launch_bounds__(64)
void prep_kernel(const float* __restrict__ B, unsigned short* __restrict__ Bfrag) {
  const int W = blockIdx.x, l = threadIdx.x;
  const int w = W >> 5, ks = W & 31;
  const int col = 16 * w + (l & 15);
  const int kb = 32 * ks + 4 * (l >> 4);
  unsigned u[4];
#pragma unroll
  for (int j = 0; j < 4; ++j) {
    int k0 = kb + 2 * (j & 1) + 16 * (j >> 1);
    u[j] = pk2(B[(size_t)k0 * N_DIM + col], B[(size_t)(k0 + 1) * N_DIM + col]);
  }
  *(uint4*)&Bfrag[((size_t)(w * 32 + ks) * 64 + l) * 8] =
      make_uint4(u[0], u[1], u[2], u[3]);
}

// ---------------------------------------------------------------------------
// K1: T = batch @ B. 256 blocks x 512 thr (8 waves, 1 block/CU).
// A-tile (64KB, linearly contiguous) staged once into LDS in fragment layout;
// B fragments prefetched upfront into registers (32 coalesced dwordx4, issued
// with the A loads -> ~40 VMEM in flight; they cross the barrier without a
// drain since the LDS barrier only forces lgkm). k-loop: ds_read_b128 + MFMA.
// ---------------------------------------------------------------------------
__global__ __launch_bounds__(512, 2)
void proj_kernel(const float* __restrict__ batch,
                 const unsigned short* __restrict__ Bfrag,
                 unsigned short* __restrict__ Tfrag, float* __restrict__ nrm) {
  __shared__ __align__(16) unsigned short Asl[32 * 64 * 8];  // 32 KB
  __shared__ float part[8][16];
  const int t = threadIdx.x, w = t >> 6, l = t & 63;
  const int blk = blockIdx.x;
  const int m0 = blk * 16;

  // ---- stage A: linear 64 KB -> bf16 fragments (coalesced 1KB/instr) ----
  {
    const float* src = batch + (size_t)m0 * K_DIM;
#pragma unroll
    for (int j = 0; j < 8; ++j) {
      int fidx = j * 512 + t;                     // f32x4 chunk index
      f32x4 v = *(const f32x4*)(src + 4 * (size_t)fidx);
      int r = fidx >> 8;                          // block row 0..15
      int q = fidx & 255;                         // k-quad within row
      int ks = q >> 3, qq = q & 7, g = qq & 3, h = qq >> 2;
      int byte = ks * 1024 + ((16 * (r + 16 * g)) ^ ((ks & 7) << 4)) + 8 * h;
      *(uint2*)((char*)Asl + byte) = make_uint2(pk2(v.x, v.y), pk2(v.z, v.w));
    }
  }

  // ---- prefetch B fragments into registers (coalesced dwordx4, L2-hit) ----
  bf16x8 bfr[32];
  {
    const unsigned short* bptr = Bfrag + ((size_t)w * 32 * 64 + l) * 8;
#pragma unroll
    for (int ks = 0; ks < 32; ++ks)
      bfr[ks] = *(const bf16x8*)(bptr + (size_t)ks * 512);
  }
  __syncthreads();

  // ---- k-loop: pure LDS + MFMA, zero barriers ----
  f32x4 acc0 = {0.f, 0.f, 0.f, 0.f}, acc1 = {0.f, 0.f, 0.f, 0.f};
#pragma unroll
  for (int ks = 0; ks < 32; ks += 2) {
    bf16x8 a0 = *(const bf16x8*)((const char*)Asl +
                   (ks * 1024 + ((l * 16) ^ ((ks & 7) << 4))));
    acc0 = __builtin_amdgcn_mfma_f32_16x16x32_bf16(bfr[ks], a0, acc0, 0, 0, 0);
    bf16x8 a1 = *(const bf16x8*)((const char*)Asl +
                   ((ks + 1) * 1024 + ((l * 16) ^ (((ks + 1) & 7) << 4))));
    acc1 = __builtin_amdgcn_mfma_f32_16x16x32_bf16(bfr[ks + 1], a1, acc1, 0, 0, 0);
  }
  f32x4 acc = acc0 + acc1;

  // ---- store T fragment (validated layout) + row norms ----
  unsigned lo = pk2(acc[0], acc[1]);
  unsigned hi = pk2(acc[2], acc[3]);
  *(uint2*)&Tfrag[(((size_t)blk * 4 + (w >> 1)) * 64 + l) * 8 + (w & 1) * 4] =
      make_uint2(lo, hi);

  float v0 = __uint_as_float(lo << 16);
  float v1 = __uint_as_float(lo & 0xffff0000u);
  float v2 = __uint_as_float(hi << 16);
  float v3 = __uint_as_float(hi & 0xffff0000u);
  float s = v0 * v0 + v1 * v1 + v2 * v2 + v3 * v3;
  s += __shfl_xor(s, 16);
  s += __shfl_xor(s, 32);   // sum over this wave's 16 cols of row l&15
  if (l < 16) part[w][l] = s;
  __syncthreads();
  if (t < 16) {
    float n = 0.f;
#pragma unroll
    for (int ww = 0; ww < 8; ++ww) n += part[ww][t];  // fixed order
    nrm[m0 + t] = n;
  }
}

// ---------------------------------------------------------------------------
// K2: out[b,i,j] = n_i + n_j - 2*(T_i.T_j). 1024 blocks x 256 thr
// (4096 waves, 4 blocks/CU). Wave = 16x16 tile: 8 frag loads, 4 MFMA, no LDS.
// ---------------------------------------------------------------------------
__global__ __launch_bounds__(256)
void dist_kernel(const unsigned short* __restrict__ Tfrag,
                 const float* __restrict__ nrm, float* __restrict__ out) {
  const int t = threadIdx.x, l = t & 63;
  const int W = blockIdx.x * 4 + (t >> 6);  // 0..4095
  const int bb = W >> 8, tile = W & 255;
  const int ti = (tile >> 4) * 16, tj = (tile & 15) * 16;
  const int rbase = bb * 256;

  bf16x8 ifr[4], jfr[4];
#pragma unroll
  for (int ks = 0; ks < 4; ++ks) {
    ifr[ks] = *(const bf16x8*)
        &Tfrag[((((size_t)bb * 16 + (ti >> 4)) * 4 + ks) * 64 + l) * 8];
    jfr[ks] = *(const bf16x8*)
        &Tfrag[((((size_t)bb * 16 + (tj >> 4)) * 4 + ks) * 64 + l) * 8];
  }

  f32x4 acc = {0.f, 0.f, 0.f, 0.f};
#pragma unroll
  for (int ks = 0; ks < 4; ++ks)
    acc = __builtin_amdgcn_mfma_f32_16x16x32_bf16(ifr[ks], jfr[ks], acc, 0, 0, 0);

  const float njv = nrm[rbase + tj + (l & 15)];
  const f32x4 ni = *(const f32x4*)&nrm[rbase + ti + 4 * (l >> 4)];
#pragma unroll
  for (int ii = 0; ii < 4; ++ii) {
    out[(size_t)(rbase + ti + 4 * (l >> 4) + ii) * 256 + tj + (l & 15)] =
        ni[ii] + njv - 2.f * acc[ii];
  }
}

extern "C" void kernel_launch(void* const* d_in, const int* in_sizes, int n_in,
                              void* d_out, int out_size, void* d_ws, size_t ws_size,
                              hipStream_t stream) {
  const float* batch = (const float*)d_in[0];  // (16,256,1024) f32
  const float* Bmat  = (const float*)d_in[1];  // (1024,128) f32
  unsigned short* Bfrag = (unsigned short*)d_ws;              // 256 KB
  unsigned short* Tfrag = Bfrag + 8 * 32 * 64 * 8;            // 1 MB
  float* nrm = (float*)(Tfrag + 256 * 4 * 64 * 8);            // 16 KB
  float* out = (float*)d_out;                                 // (16,256,256) f32

  prep_kernel<<<256, 64, 0, stream>>>(Bmat, Bfrag);
  proj_kernel<<<256, 512, 0, stream>>>(batch, Bfrag, Tfrag, nrm);
  dist_kernel<<<1024, 256, 0, stream>>>(Tfrag, nrm, out);
}